// Round 1
// 398.145 us; speedup vs baseline: 1.0110x; 1.0110x over previous
//
#include <hip/hip_runtime.h>

typedef unsigned short u16;
typedef __attribute__((ext_vector_type(8))) __bf16 bf16x8;
typedef __attribute__((ext_vector_type(4))) float floatx4;

__device__ inline float bf2f(u16 u) {
  union { unsigned u; float f; } v; v.u = ((unsigned)u) << 16; return v.f;
}
__device__ inline u16 f2bf(float f) {
  union { float f; unsigned u; } v; v.f = f;
  unsigned r = v.u + 0x7fffu + ((v.u >> 16) & 1u);
  return (u16)(r >> 16);
}

__device__ inline void glds16(const u16* g, u16* l) {
  __builtin_amdgcn_global_load_lds((const __attribute__((address_space(1))) void*)g,
                                   (__attribute__((address_space(3))) void*)l, 16, 0, 0);
}

// ---------------- dtype probe: fp32-as-u16 halves have wild exponents ----------------
__global__ __launch_bounds__(256) void detect_k(const u16* __restrict__ w, int* flag)
{
  __shared__ int cnt;
  if (threadIdx.x == 0) cnt = 0;
  __syncthreads();
  int c = 0;
  for (int i = threadIdx.x; i < 16384; i += 256) {
    const int e = (w[i] >> 7) & 0xFF;
    if (e < 64 || e > 191) ++c;
  }
  atomicAdd(&cnt, c);
  __syncthreads();
  if (threadIdx.x == 0) *flag = (cnt > 256) ? 1 : 0;   // 1 => inputs are fp32
}

// ---------------- x -> bf16 (copy or downcast), 4 elems/thread ----------------
__global__ __launch_bounds__(256) void cast_x_k(const void* __restrict__ in,
                                                u16* __restrict__ out,
                                                int n4, const int* __restrict__ flag)
{
  const int i = blockIdx.x * 256 + threadIdx.x;
  if (i >= n4) return;
  if (*flag) {
    const float4 v = ((const float4*)in)[i];
    u16 o0 = f2bf(v.x), o1 = f2bf(v.y), o2 = f2bf(v.z), o3 = f2bf(v.w);
    uint2 p; p.x = (unsigned)o0 | ((unsigned)o1 << 16); p.y = (unsigned)o2 | ((unsigned)o3 << 16);
    ((uint2*)out)[i] = p;
  } else {
    ((uint2*)out)[i] = ((const uint2*)in)[i];
  }
}

// ---------------- cast+transpose: in [R,C] (flag? f32 : bf16) -> bf16 [C,R] ----------------
__global__ __launch_bounds__(256) void ct_transpose_k(const void* __restrict__ in,
                                                      u16* __restrict__ out,
                                                      int R, int C, const int* __restrict__ flag)
{
  __shared__ u16 tile[32][33];
  const int f = *flag;
  const int c0 = blockIdx.x * 32, r0 = blockIdx.y * 32;
  const int tx = threadIdx.x & 31, ty = threadIdx.x >> 5;
#pragma unroll
  for (int i = ty; i < 32; i += 8) {
    const size_t idx = (size_t)(r0 + i) * C + (c0 + tx);
    tile[i][tx] = f ? f2bf(((const float*)in)[idx]) : ((const u16*)in)[idx];
  }
  __syncthreads();
#pragma unroll
  for (int i = ty; i < 32; i += 8)
    out[(size_t)(c0 + i) * R + (r0 + tx)] = tile[tx][i];
}

// ---------------- bias -> fp32 ----------------
__global__ __launch_bounds__(256) void bias_cast_k(const void* __restrict__ in,
                                                   float* __restrict__ out,
                                                   int n, const int* __restrict__ flag)
{
  const int i = blockIdx.x * 256 + threadIdx.x;
  if (i >= n) return;
  out[i] = *flag ? ((const float*)in)[i] : bf2f(((const u16*)in)[i]);
}

// ---------------- GEMM C[M,N] = A[M,K] @ Bt[N,K]^T (+bias), bf16 MFMA ----------------
// 256x256 tile, 8 waves (2M x 4N), BK=32, 4-slot LDS ring (128 KiB), deep pipeline:
// stages issued 3 K-tiles ahead of use, counted s_waitcnt vmcnt(8) once per K-tile
// (never drained to 0 in steady state), raw s_barrier (no vmcnt drain), setprio(1)
// around each 16-MFMA cluster, XOR-swizzled LDS (16B slot h ^= line&7 within 128B
// lines of 2 rows) with inverse-swizzled per-lane global source + linear
// global_load_lds dest, bijective XCD swizzle + M-major tile order.
// Requires M%256==0, N%256==0, K%32==0, K>=128.
__global__ __launch_bounds__(512) void gemm256(
    const u16* __restrict__ A, const u16* __restrict__ Bt,
    const float* __restrict__ bias, void* __restrict__ C,
    int M, int N, int K, const int* __restrict__ flag, int flagOut)
{
  __shared__ u16 smem[65536];   // A ring: [0..32767], B ring: [32768..65535]
  const int t = threadIdx.x;
  const int wave = t >> 6, lane = t & 63;
  const int quad = lane >> 4, l15 = lane & 15;
  const int wm = wave >> 2, wn = wave & 3;

  // bijective XCD swizzle (nwg%8 != 0 safe), then M-major so consecutive blocks
  // in an XCD chunk share the B-panel (384 KB, L2-resident)
  const int nwg = gridDim.x;
  const int q = nwg >> 3, r8 = nwg & 7;
  const int xcd = blockIdx.x & 7, loc = blockIdx.x >> 3;
  const int wg = (xcd < r8 ? xcd * (q + 1) : r8 * (q + 1) + (xcd - r8) * q) + loc;
  const int MT = M >> 8;
  const int mt = wg % MT, ntile = wg / MT;
  const size_t m0 = (size_t)mt << 8;
  const size_t n0 = (size_t)ntile << 8;

  // LDS read offsets (u16 units within one 8192-u16 buffer).
  // Layout: line = row>>1 (128 B), slot h = (row&1)*4 + kgroup, stored h^(line&7).
  int addrA[8], addrB[4];
#pragma unroll
  for (int i = 0; i < 8; ++i) {
    const int row = wm * 128 + i * 16 + l15;
    const int hs = (((row & 1) << 2) | quad) ^ ((row >> 1) & 7);
    addrA[i] = (row >> 1) * 64 + hs * 8;
  }
#pragma unroll
  for (int j = 0; j < 4; ++j) {
    const int row = wn * 64 + j * 16 + l15;
    const int hs = (((row & 1) << 2) | quad) ^ ((row >> 1) & 7);
    addrB[j] = (row >> 1) * 64 + hs * 8;
  }

  // staging: issue p covers stored slots S = p*512 + wave*64 + lane; invert swizzle
  // to find the (row, kgroup) that must be fetched into slot S.
  const u16* aSrc[2]; const u16* bSrc[2]; int dstOff[2];
#pragma unroll
  for (int p = 0; p < 2; ++p) {
    const int S = p * 512 + wave * 64 + lane;
    const int line = S >> 3;
    const int h = (S & 7) ^ (line & 7);
    const int row = line * 2 + (h >> 2);
    const int g = (h & 3) * 8;
    aSrc[p] = A + (m0 + row) * (size_t)K + g;
    bSrc[p] = Bt + (n0 + row) * (size_t)K + g;
    dstOff[p] = p * 4096 + wave * 512;   // u16 units; HW adds lane*16 B
  }

  const int NTk = K >> 5;
  floatx4 acc[8][4] = {};

  // prologue: stage K-tiles 0..2 into ring slots 0..2
#pragma unroll
  for (int pt = 0; pt < 3; ++pt) {
#pragma unroll
    for (int p = 0; p < 2; ++p) glds16(aSrc[p] + pt * 32, smem + pt * 8192 + dstOff[p]);
#pragma unroll
    for (int p = 0; p < 2; ++p) glds16(bSrc[p] + pt * 32, smem + 32768 + pt * 8192 + dstOff[p]);
  }
  asm volatile("s_waitcnt vmcnt(8)" ::: "memory");   // tile 0 landed; 1,2 in flight
  __builtin_amdgcn_s_barrier();

  for (int kt = 0; kt < NTk; ++kt) {
    const int rb = kt & 3;
    const u16* sA = smem + rb * 8192;
    const u16* sB = smem + 32768 + rb * 8192;
    const bool pf = (kt + 3 < NTk);
    const int pre = (kt + 3) * 32;
    const int pr = (kt + 3) & 3;   // == (kt-1)&3: fully consumed + barrier'd

    // ---- phase 0: m-frags 0..3 x n-frags 0..3 ----
    bf16x8 a[4], b[4];
#pragma unroll
    for (int i = 0; i < 4; ++i) a[i] = *(const bf16x8*)(sA + addrA[i]);
#pragma unroll
    for (int j = 0; j < 4; ++j) b[j] = *(const bf16x8*)(sB + addrB[j]);
    if (pf) {
      glds16(aSrc[0] + pre, smem + pr * 8192 + dstOff[0]);
      glds16(aSrc[1] + pre, smem + pr * 8192 + dstOff[1]);
    }
    __builtin_amdgcn_s_barrier();
    asm volatile("s_waitcnt lgkmcnt(0)");
    __builtin_amdgcn_s_setprio(1);
#pragma unroll
    for (int i = 0; i < 4; ++i)
#pragma unroll
      for (int j = 0; j < 4; ++j)
        acc[i][j] = __builtin_amdgcn_mfma_f32_16x16x32_bf16(a[i], b[j], acc[i][j], 0, 0, 0);
    __builtin_amdgcn_s_setprio(0);
    __builtin_amdgcn_s_barrier();

    // ---- phase 1: m-frags 4..7, reuse B frags ----
#pragma unroll
    for (int i = 0; i < 4; ++i) a[i] = *(const bf16x8*)(sA + addrA[4 + i]);
    if (pf) {
      glds16(bSrc[0] + pre, smem + 32768 + pr * 8192 + dstOff[0]);
      glds16(bSrc[1] + pre, smem + 32768 + pr * 8192 + dstOff[1]);
    }
    __builtin_amdgcn_s_barrier();
    asm volatile("s_waitcnt lgkmcnt(0)");
    __builtin_amdgcn_s_setprio(1);
#pragma unroll
    for (int i = 0; i < 4; ++i)
#pragma unroll
      for (int j = 0; j < 4; ++j)
        acc[4 + i][j] = __builtin_amdgcn_mfma_f32_16x16x32_bf16(a[i], b[j], acc[4 + i][j], 0, 0, 0);
    __builtin_amdgcn_s_setprio(0);
    // counted vmcnt once per K-tile: keep 2 K-tiles (8 loads) in flight
    if (kt < NTk - 3)       asm volatile("s_waitcnt vmcnt(8)" ::: "memory");
    else if (kt == NTk - 3) asm volatile("s_waitcnt vmcnt(4)" ::: "memory");
    else if (kt == NTk - 2) asm volatile("s_waitcnt vmcnt(0)" ::: "memory");
    __builtin_amdgcn_s_barrier();
  }

  // -------- epilogue: per-wave LDS repack -> coalesced 16B stores --------
  float bvj[4];
#pragma unroll
  for (int j = 0; j < 4; ++j)
    bvj[j] = bias ? bias[n0 + wn * 64 + j * 16 + l15] : 0.0f;

  if (flagOut && (*flag)) {
    // fp32 output: per m-frag 16 rows x 64 cols (stride 68 f32)
    float* scrf = (float*)smem + wave * 1088;
    float* Cf = (float*)C;
#pragma unroll
    for (int i = 0; i < 8; ++i) {
#pragma unroll
      for (int j = 0; j < 4; ++j)
#pragma unroll
        for (int rr = 0; rr < 4; ++rr)
          scrf[(quad * 4 + rr) * 68 + j * 16 + l15] = acc[i][j][rr] + bvj[j];
#pragma unroll
      for (int u = lane; u < 256; u += 64) {
        const int row = u >> 4, gr = u & 15;
        float4 vv = *(const float4*)(scrf + row * 68 + gr * 4);
        *(float4*)(Cf + (m0 + wm * 128 + i * 16 + row) * (size_t)N + n0 + wn * 64 + gr * 4) = vv;
      }
    }
  } else {
    // bf16 output: per m-frag 16 rows x 64 cols (stride 72 u16)
    u16* scr = smem + wave * 1152;
    u16* Cb = (u16*)C;
#pragma unroll
    for (int i = 0; i < 8; ++i) {
#pragma unroll
      for (int j = 0; j < 4; ++j)
#pragma unroll
        for (int rr = 0; rr < 4; ++rr)
          scr[(quad * 4 + rr) * 72 + j * 16 + l15] = f2bf(acc[i][j][rr] + bvj[j]);
#pragma unroll
      for (int u = lane; u < 128; u += 64) {
        const int row = u >> 3, gr = u & 7;
        int4 vv = *(const int4*)(scr + row * 72 + gr * 8);
        *(int4*)(Cb + (m0 + wm * 128 + i * 16 + row) * (size_t)N + n0 + wn * 64 + gr * 8) = vv;
      }
    }
  }
}

// ---------------- windowed attention ----------------
// one block (4 waves) per (b, l, head). K staged in LDS (XOR-64), V^T and P at
// stride 208 (2-way banks = free). LDS total 79.2 KB -> 2 blocks/CU.
__global__ __launch_bounds__(256, 2) void attn_win(
    const u16* __restrict__ qkv, u16* __restrict__ o)
{
  __shared__ u16 Ks[196 * 64];      // slot16B = row*8 + (g ^ (row&7))
  __shared__ u16 Vt[64 * 208];      // Vt[d][n], cols >=196 zero
  __shared__ u16 Pb[4][16 * 208];   // per-wave strip
  __shared__ int gtok[208];

  const int bid = blockIdx.x;
  const int h = bid % 12;
  const int l = (bid / 12) % 16;
  const int b = bid / 192;
  const int wr0 = (l >> 2) * 14, wc0 = (l & 3) * 14;
  const int baseTok = b * 3136;

  const int t = threadIdx.x, wave = t >> 6, lane = t & 63;
  const int quad = lane >> 4, l15 = lane & 15;

  if (t < 208) {
    const int nn = t < 196 ? t : 195;
    gtok[t] = baseTok + (wr0 + nn / 14) * 56 + wc0 + nn % 14;
  }
  __syncthreads();

  // stage K (rows 0..195, 8 d-groups, XOR layout)
  for (int u = t; u < 196 * 8; u += 256) {
    const int row = u >> 3, gg = u & 7;
    int4 kv = *(const int4*)(qkv + (size_t)gtok[row] * 2304 + 768 + h * 64 + gg * 8);
    *(int4*)(Ks + (row * 8 + (gg ^ (row & 7))) * 8) = kv;
  }
  // stage V transposed: Vt[d][n]
  for (int u = t; u < 208 * 8; u += 256) {
    const int n = u >> 3, dg = u & 7;
    int4 vv = {0, 0, 0, 0};
    if (n < 196)
      vv = *(const int4*)(qkv + (size_t)gtok[n] * 2304 + 1536 + h * 64 + dg * 8);
    const u16* pv = (const u16*)&vv;
#pragma unroll
    for (int j = 0; j < 8; ++j) Vt[(dg * 8 + j) * 208 + n] = pv[j];
  }
  __syncthreads();

  u16* Pw = &Pb[wave][0];
  const bf16x8 zerov = {};

  for (int rt = wave; rt < 13; rt += 4) {
    const int n0r = rt * 16;
    int qn = n0r + l15; if (qn > 195) qn = 195;
    const u16* qrow = qkv + (size_t)gtok[qn] * 2304 + h * 64;
    const bf16x8 aq0 = *(const bf16x8*)(qrow + quad * 8);
    const bf16x8 aq1 = *(const bf16x8*)(qrow + 32 + quad * 8);

    floatx4 s[13];
#pragma unroll
    for (int ct = 0; ct < 13; ++ct) {
      int kr = ct * 16 + l15; if (kr > 195) kr = 195;
      const bf16x8 bk0 = *(const bf16x8*)(Ks + (kr * 8 + (quad ^ (kr & 7))) * 8);
      const bf16x8 bk1 = *(const bf16x8*)(Ks + (kr * 8 + ((quad + 4) ^ (kr & 7))) * 8);
      floatx4 z = {};
      z = __builtin_amdgcn_mfma_f32_16x16x32_bf16(aq0, bk0, z, 0, 0, 0);
      z = __builtin_amdgcn_mfma_f32_16x16x32_bf16(aq1, bk1, z, 0, 0, 0);
      s[ct] = z;
    }

    // softmax: col = ct*16+l15, rows = n0r + quad*4 + r
    float mx[4], sm[4];
#pragma unroll
    for (int r = 0; r < 4; ++r) mx[r] = -3e38f;
#pragma unroll
    for (int ct = 0; ct < 13; ++ct) {
      const bool maskct = (ct == 12) && (l15 >= 4);
#pragma unroll
      for (int r = 0; r < 4; ++r) {
        float v = s[ct][r] * 0.125f;
        if (maskct) v = -3e38f;
        s[ct][r] = v;
        mx[r] = fmaxf(mx[r], v);
      }
    }
#pragma unroll
    for (int r = 0; r < 4; ++r)
      for (int off = 1; off < 16; off <<= 1)
        mx[r] = fmaxf(mx[r], __shfl_xor(mx[r], off, 64));
#pragma unroll
    for (int r = 0; r < 4; ++r) sm[r] = 0.0f;
#pragma unroll
    for (int ct = 0; ct < 13; ++ct)
#pragma unroll
      for (int r = 0; r < 4; ++r) {
        const float p = __expf(s[ct][r] - mx[r]);
        s[ct][r] = p;
        sm[r] += p;
      }
#pragma unroll
    for (int r = 0; r < 4; ++r)
      for (int off = 1; off < 16; off <<= 1)
        sm[r] += __shfl_xor(sm[r], off, 64);

    // P -> LDS (A-layout round trip); cols 0..207 fully covered
#pragma unroll
    for (int ct = 0; ct < 13; ++ct)
#pragma unroll
      for (int r = 0; r < 4; ++r)
        Pw[(quad * 4 + r) * 208 + ct * 16 + l15] = f2bf(s[ct][r]);

    // O = P @ V: 6 full K=32 steps + masked tail (k 192..207 real)
    floatx4 oacc[4] = {};
#pragma unroll
    for (int ks = 0; ks < 6; ++ks) {
      const bf16x8 ap = *(const bf16x8*)(Pw + l15 * 208 + ks * 32 + quad * 8);
#pragma unroll
      for (int nt = 0; nt < 4; ++nt) {
        const bf16x8 bv = *(const bf16x8*)(Vt + (nt * 16 + l15) * 208 + ks * 32 + quad * 8);
        oacc[nt] = __builtin_amdgcn_mfma_f32_16x16x32_bf16(ap, bv, oacc[nt], 0, 0, 0);
      }
    }
    {
      const int off = 192 + (quad & 1) * 8;
      bf16x8 ap = *(const bf16x8*)(Pw + l15 * 208 + off);
      if (quad >= 2) ap = zerov;
#pragma unroll
      for (int nt = 0; nt < 4; ++nt) {
        const bf16x8 bv = *(const bf16x8*)(Vt + (nt * 16 + l15) * 208 + off);
        oacc[nt] = __builtin_amdgcn_mfma_f32_16x16x32_bf16(ap, bv, oacc[nt], 0, 0, 0);
      }
    }

    float rs[4];
#pragma unroll
    for (int r = 0; r < 4; ++r) rs[r] = 1.0f / sm[r];

    // O -> Pw repack -> coalesced 16B stores
#pragma unroll
    for (int nt = 0; nt < 4; ++nt)
#pragma unroll
      for (int r = 0; r < 4; ++r)
        Pw[(quad * 4 + r) * 208 + nt * 16 + l15] = f2bf(oacc[nt][r] * rs[r]);
#pragma unroll
    for (int u = lane; u < 128; u += 64) {
      const int row = u >> 3, gr = u & 7;
      const int n = n0r + row;
      if (n < 196) {
        int4 vv = *(const int4*)(Pw + row * 208 + gr * 8);
        *(int4*)(o + (size_t)gtok[n] * 768 + h * 64 + gr * 8) = vv;
      }
    }
  }
}

extern "C" void kernel_launch(void* const* d_in, const int* in_sizes, int n_in,
                              void* d_out, int out_size, void* d_ws, size_t ws_size,
                              hipStream_t stream)
{
  const void* x     = d_in[0];  // [8,3136,768]   fp32 or bf16
  const void* wqkv  = d_in[1];  // [768,2304]
  const void* wproj = d_in[2];  // [768,768]
  const void* bproj = d_in[3];  // [768]

  char* ws = (char*)d_ws;
  int*   flag   = (int*)ws;                         // 16 B
  float* bprojF = (float*)(ws + 16);                // 768 f32
  u16*   wqkvT  = (u16*)(ws + 4096);                // 2304*768 bf16
  u16*   wprojT = (u16*)(ws + 3543040);             // 768*768  bf16
  u16*   qkvbuf = (u16*)(ws + 4722688);             // 25088*2304 bf16
  u16*   xb     = (u16*)(ws + 120328192);           // 25088*768 bf16 (reused as attn out)
  u16*   attno  = xb;

  detect_k<<<1, 256, 0, stream>>>((const u16*)wqkv, flag);
  cast_x_k<<<dim3(18816), 256, 0, stream>>>(x, xb, 4816896, flag);
  ct_transpose_k<<<dim3(72, 24), 256, 0, stream>>>(wqkv, wqkvT, 768, 2304, flag);
  ct_transpose_k<<<dim3(24, 24), 256, 0, stream>>>(wproj, wprojT, 768, 768, flag);
  bias_cast_k<<<dim3(3), 256, 0, stream>>>(bproj, bprojF, 768, flag);

  // QKV: M=25088 (98 tiles), N=2304 (9 tiles), K=768 -> 882 blocks
  gemm256<<<dim3(882), 512, 0, stream>>>(xb, wqkvT, (const float*)nullptr, qkvbuf,
                                         25088, 2304, 768, flag, 0);
  attn_win<<<dim3(1536), 256, 0, stream>>>(qkvbuf, attno);
  // proj: M=25088 (98 tiles), N=768 (3 tiles), K=768 -> 294 blocks
  gemm256<<<dim3(294), 512, 0, stream>>>(attno, wprojT, bprojF, d_out,
                                         25088, 768, 768, flag, 1);
}

// Round 2
// 395.235 us; speedup vs baseline: 1.0185x; 1.0074x over previous
//
#include <hip/hip_runtime.h>

typedef unsigned short u16;
typedef __attribute__((ext_vector_type(8))) __bf16 bf16x8;
typedef __attribute__((ext_vector_type(4))) float floatx4;

__device__ inline float bf2f(u16 u) {
  union { unsigned u; float f; } v; v.u = ((unsigned)u) << 16; return v.f;
}
__device__ inline u16 f2bf(float f) {
  union { float f; unsigned u; } v; v.f = f;
  unsigned r = v.u + 0x7fffu + ((v.u >> 16) & 1u);
  return (u16)(r >> 16);
}

__device__ inline void glds16(const u16* g, u16* l) {
  __builtin_amdgcn_global_load_lds((const __attribute__((address_space(1))) void*)g,
                                   (__attribute__((address_space(3))) void*)l, 16, 0, 0);
}

// ---------------- dtype probe: fp32-as-u16 halves have wild exponents ----------------
__global__ __launch_bounds__(256) void detect_k(const u16* __restrict__ w, int* flag)
{
  __shared__ int cnt;
  if (threadIdx.x == 0) cnt = 0;
  __syncthreads();
  int c = 0;
  for (int i = threadIdx.x; i < 16384; i += 256) {
    const int e = (w[i] >> 7) & 0xFF;
    if (e < 64 || e > 191) ++c;
  }
  atomicAdd(&cnt, c);
  __syncthreads();
  if (threadIdx.x == 0) *flag = (cnt > 256) ? 1 : 0;   // 1 => inputs are fp32
}

// ---------------- x -> bf16 (copy or downcast), 4 elems/thread ----------------
__global__ __launch_bounds__(256) void cast_x_k(const void* __restrict__ in,
                                                u16* __restrict__ out,
                                                int n4, const int* __restrict__ flag)
{
  const int i = blockIdx.x * 256 + threadIdx.x;
  if (i >= n4) return;
  if (*flag) {
    const float4 v = ((const float4*)in)[i];
    u16 o0 = f2bf(v.x), o1 = f2bf(v.y), o2 = f2bf(v.z), o3 = f2bf(v.w);
    uint2 p; p.x = (unsigned)o0 | ((unsigned)o1 << 16); p.y = (unsigned)o2 | ((unsigned)o3 << 16);
    ((uint2*)out)[i] = p;
  } else {
    ((uint2*)out)[i] = ((const uint2*)in)[i];
  }
}

// ---------------- cast+transpose: in [R,C] (flag? f32 : bf16) -> bf16 [C,R] ----------------
__global__ __launch_bounds__(256) void ct_transpose_k(const void* __restrict__ in,
                                                      u16* __restrict__ out,
                                                      int R, int C, const int* __restrict__ flag)
{
  __shared__ u16 tile[32][33];
  const int f = *flag;
  const int c0 = blockIdx.x * 32, r0 = blockIdx.y * 32;
  const int tx = threadIdx.x & 31, ty = threadIdx.x >> 5;
#pragma unroll
  for (int i = ty; i < 32; i += 8) {
    const size_t idx = (size_t)(r0 + i) * C + (c0 + tx);
    tile[i][tx] = f ? f2bf(((const float*)in)[idx]) : ((const u16*)in)[idx];
  }
  __syncthreads();
#pragma unroll
  for (int i = ty; i < 32; i += 8)
    out[(size_t)(c0 + i) * R + (r0 + tx)] = tile[tx][i];
}

// ---------------- bias -> fp32 ----------------
__global__ __launch_bounds__(256) void bias_cast_k(const void* __restrict__ in,
                                                   float* __restrict__ out,
                                                   int n, const int* __restrict__ flag)
{
  const int i = blockIdx.x * 256 + threadIdx.x;
  if (i >= n) return;
  out[i] = *flag ? ((const float*)in)[i] : bf2f(((const u16*)in)[i]);
}

// ---------------- GEMM C[M,N] = A[M,K] @ Bt[N,K]^T (+bias), bf16 MFMA ----------------
// 256x256 tile, 8 waves (2M x 4N), BK=32, 4-slot LDS ring (128 KiB).
// ONE barrier per K-tile (fused into a single asm with the counted vmcnt): with the
// ring, slot-overwrite protection and stage-visibility need only the end-of-tile
// barrier; removing the intra-tile barrier pair lets waves skew so LDS-read drain
// overlaps the MFMA clusters of earlier waves (per-tile = max(LDS,MFMA), not sum).
// Counted s_waitcnt vmcnt(8) keeps 2 K-tiles of DMA in flight (never drained to 0
// in steady state). XOR-swizzled LDS (16B slot h ^= line&7 within 128B lines of
// 2 rows), inverse-swizzled per-lane global source + linear global_load_lds dest,
// bijective XCD swizzle + M-major tile order, setprio(1) around MFMA cluster.
// Requires M%256==0, N%256==0, K%32==0, K>=128.
__global__ __launch_bounds__(512) void gemm256(
    const u16* __restrict__ A, const u16* __restrict__ Bt,
    const float* __restrict__ bias, void* __restrict__ C,
    int M, int N, int K, const int* __restrict__ flag, int flagOut)
{
  __shared__ u16 smem[65536];   // A ring: [0..32767], B ring: [32768..65535]
  const int t = threadIdx.x;
  const int wave = t >> 6, lane = t & 63;
  const int quad = lane >> 4, l15 = lane & 15;
  const int wm = wave >> 2, wn = wave & 3;

  // bijective XCD swizzle (nwg%8 != 0 safe), then M-major so consecutive blocks
  // in an XCD chunk share the B-panel (384 KB, L2-resident)
  const int nwg = gridDim.x;
  const int q = nwg >> 3, r8 = nwg & 7;
  const int xcd = blockIdx.x & 7, loc = blockIdx.x >> 3;
  const int wg = (xcd < r8 ? xcd * (q + 1) : r8 * (q + 1) + (xcd - r8) * q) + loc;
  const int MT = M >> 8;
  const int mt = wg % MT, ntile = wg / MT;
  const size_t m0 = (size_t)mt << 8;
  const size_t n0 = (size_t)ntile << 8;

  // LDS read offsets (u16 units within one 8192-u16 buffer).
  // Layout: line = row>>1 (128 B), slot h = (row&1)*4 + kgroup, stored h^(line&7).
  int addrA[8], addrB[4];
#pragma unroll
  for (int i = 0; i < 8; ++i) {
    const int row = wm * 128 + i * 16 + l15;
    const int hs = (((row & 1) << 2) | quad) ^ ((row >> 1) & 7);
    addrA[i] = (row >> 1) * 64 + hs * 8;
  }
#pragma unroll
  for (int j = 0; j < 4; ++j) {
    const int row = wn * 64 + j * 16 + l15;
    const int hs = (((row & 1) << 2) | quad) ^ ((row >> 1) & 7);
    addrB[j] = (row >> 1) * 64 + hs * 8;
  }

  // staging: issue p covers stored slots S = p*512 + wave*64 + lane; invert swizzle
  // to find the (row, kgroup) that must be fetched into slot S.
  const u16* aSrc[2]; const u16* bSrc[2]; int dstOff[2];
#pragma unroll
  for (int p = 0; p < 2; ++p) {
    const int S = p * 512 + wave * 64 + lane;
    const int line = S >> 3;
    const int h = (S & 7) ^ (line & 7);
    const int row = line * 2 + (h >> 2);
    const int g = (h & 3) * 8;
    aSrc[p] = A + (m0 + row) * (size_t)K + g;
    bSrc[p] = Bt + (n0 + row) * (size_t)K + g;
    dstOff[p] = p * 4096 + wave * 512;   // u16 units; HW adds lane*16 B
  }

  const int NTk = K >> 5;
  floatx4 acc[8][4] = {};

  // prologue: stage K-tiles 0..2 into ring slots 0..2
#pragma unroll
  for (int pt = 0; pt < 3; ++pt) {
#pragma unroll
    for (int p = 0; p < 2; ++p) glds16(aSrc[p] + pt * 32, smem + pt * 8192 + dstOff[p]);
#pragma unroll
    for (int p = 0; p < 2; ++p) glds16(bSrc[p] + pt * 32, smem + 32768 + pt * 8192 + dstOff[p]);
  }
  // tile 0 landed; tiles 1,2 in flight. Fused wait+barrier so no memory op can
  // slip between this wave's vmcnt and the cross-wave sync.
  asm volatile("s_waitcnt vmcnt(8)\n\ts_barrier" ::: "memory");

  for (int kt = 0; kt < NTk; ++kt) {
    const int rb = kt & 3;
    const u16* sA = smem + rb * 8192;
    const u16* sB = smem + 32768 + rb * 8192;

    // issue next-next-next tile's DMA first (earliest HBM issue; writes slot
    // (kt-1)&3 whose readers all finished before the end-of-(kt-1) barrier)
    if (kt + 3 < NTk) {
      const int pre = (kt + 3) * 32;
      const int pr = (kt + 3) & 3;
      glds16(aSrc[0] + pre, smem + pr * 8192 + dstOff[0]);
      glds16(aSrc[1] + pre, smem + pr * 8192 + dstOff[1]);
      glds16(bSrc[0] + pre, smem + 32768 + pr * 8192 + dstOff[0]);
      glds16(bSrc[1] + pre, smem + 32768 + pr * 8192 + dstOff[1]);
    }

    // B first so the first MFMA's lgkm wait covers only 5 loads, not 12;
    // compiler inserts fine-grained lgkmcnt between reads and consuming MFMAs.
    bf16x8 b[4], a[8];
#pragma unroll
    for (int j = 0; j < 4; ++j) b[j] = *(const bf16x8*)(sB + addrB[j]);
#pragma unroll
    for (int i = 0; i < 8; ++i) a[i] = *(const bf16x8*)(sA + addrA[i]);

    __builtin_amdgcn_s_setprio(1);
#pragma unroll
    for (int i = 0; i < 8; ++i)
#pragma unroll
      for (int j = 0; j < 4; ++j)
        acc[i][j] = __builtin_amdgcn_mfma_f32_16x16x32_bf16(a[i], b[j], acc[i][j], 0, 0, 0);
    __builtin_amdgcn_s_setprio(0);

    // ONE fused counted-wait + barrier per K-tile: guarantees tile kt+1's DMA
    // (from ALL waves) has landed; never drains vmcnt to 0 until the ramp-down.
    if (kt < NTk - 3)       asm volatile("s_waitcnt vmcnt(8)\n\ts_barrier" ::: "memory");
    else if (kt == NTk - 3) asm volatile("s_waitcnt vmcnt(4)\n\ts_barrier" ::: "memory");
    else if (kt == NTk - 2) asm volatile("s_waitcnt vmcnt(0)\n\ts_barrier" ::: "memory");
    else                    asm volatile("s_barrier" ::: "memory");
  }

  // -------- epilogue: per-wave LDS repack -> coalesced 16B stores --------
  float bvj[4];
#pragma unroll
  for (int j = 0; j < 4; ++j)
    bvj[j] = bias ? bias[n0 + wn * 64 + j * 16 + l15] : 0.0f;

  if (flagOut && (*flag)) {
    // fp32 output: per m-frag 16 rows x 64 cols (stride 68 f32)
    float* scrf = (float*)smem + wave * 1088;
    float* Cf = (float*)C;
#pragma unroll
    for (int i = 0; i < 8; ++i) {
#pragma unroll
      for (int j = 0; j < 4; ++j)
#pragma unroll
        for (int rr = 0; rr < 4; ++rr)
          scrf[(quad * 4 + rr) * 68 + j * 16 + l15] = acc[i][j][rr] + bvj[j];
#pragma unroll
      for (int u = lane; u < 256; u += 64) {
        const int row = u >> 4, gr = u & 15;
        float4 vv = *(const float4*)(scrf + row * 68 + gr * 4);
        *(float4*)(Cf + (m0 + wm * 128 + i * 16 + row) * (size_t)N + n0 + wn * 64 + gr * 4) = vv;
      }
    }
  } else {
    // bf16 output: per m-frag 16 rows x 64 cols (stride 72 u16)
    u16* scr = smem + wave * 1152;
    u16* Cb = (u16*)C;
#pragma unroll
    for (int i = 0; i < 8; ++i) {
#pragma unroll
      for (int j = 0; j < 4; ++j)
#pragma unroll
        for (int rr = 0; rr < 4; ++rr)
          scr[(quad * 4 + rr) * 72 + j * 16 + l15] = f2bf(acc[i][j][rr] + bvj[j]);
#pragma unroll
      for (int u = lane; u < 128; u += 64) {
        const int row = u >> 3, gr = u & 7;
        int4 vv = *(const int4*)(scr + row * 72 + gr * 8);
        *(int4*)(Cb + (m0 + wm * 128 + i * 16 + row) * (size_t)N + n0 + wn * 64 + gr * 8) = vv;
      }
    }
  }
}

// ---------------- windowed attention ----------------
// one block (4 waves) per (b, l, head). K staged in LDS (XOR-64), V^T and P at
// stride 208 (2-way banks = free). LDS total 79.2 KB -> 2 blocks/CU.
__global__ __launch_bounds__(256, 2) void attn_win(
    const u16* __restrict__ qkv, u16* __restrict__ o)
{
  __shared__ u16 Ks[196 * 64];      // slot16B = row*8 + (g ^ (row&7))
  __shared__ u16 Vt[64 * 208];      // Vt[d][n], cols >=196 zero
  __shared__ u16 Pb[4][16 * 208];   // per-wave strip
  __shared__ int gtok[208];

  const int bid = blockIdx.x;
  const int h = bid % 12;
  const int l = (bid / 12) % 16;
  const int b = bid / 192;
  const int wr0 = (l >> 2) * 14, wc0 = (l & 3) * 14;
  const int baseTok = b * 3136;

  const int t = threadIdx.x, wave = t >> 6, lane = t & 63;
  const int quad = lane >> 4, l15 = lane & 15;

  if (t < 208) {
    const int nn = t < 196 ? t : 195;
    gtok[t] = baseTok + (wr0 + nn / 14) * 56 + wc0 + nn % 14;
  }
  __syncthreads();

  // stage K (rows 0..195, 8 d-groups, XOR layout)
  for (int u = t; u < 196 * 8; u += 256) {
    const int row = u >> 3, gg = u & 7;
    int4 kv = *(const int4*)(qkv + (size_t)gtok[row] * 2304 + 768 + h * 64 + gg * 8);
    *(int4*)(Ks + (row * 8 + (gg ^ (row & 7))) * 8) = kv;
  }
  // stage V transposed: Vt[d][n]
  for (int u = t; u < 208 * 8; u += 256) {
    const int n = u >> 3, dg = u & 7;
    int4 vv = {0, 0, 0, 0};
    if (n < 196)
      vv = *(const int4*)(qkv + (size_t)gtok[n] * 2304 + 1536 + h * 64 + dg * 8);
    const u16* pv = (const u16*)&vv;
#pragma unroll
    for (int j = 0; j < 8; ++j) Vt[(dg * 8 + j) * 208 + n] = pv[j];
  }
  __syncthreads();

  u16* Pw = &Pb[wave][0];
  const bf16x8 zerov = {};

  for (int rt = wave; rt < 13; rt += 4) {
    const int n0r = rt * 16;
    int qn = n0r + l15; if (qn > 195) qn = 195;
    const u16* qrow = qkv + (size_t)gtok[qn] * 2304 + h * 64;
    const bf16x8 aq0 = *(const bf16x8*)(qrow + quad * 8);
    const bf16x8 aq1 = *(const bf16x8*)(qrow + 32 + quad * 8);

    floatx4 s[13];
#pragma unroll
    for (int ct = 0; ct < 13; ++ct) {
      int kr = ct * 16 + l15; if (kr > 195) kr = 195;
      const bf16x8 bk0 = *(const bf16x8*)(Ks + (kr * 8 + (quad ^ (kr & 7))) * 8);
      const bf16x8 bk1 = *(const bf16x8*)(Ks + (kr * 8 + ((quad + 4) ^ (kr & 7))) * 8);
      floatx4 z = {};
      z = __builtin_amdgcn_mfma_f32_16x16x32_bf16(aq0, bk0, z, 0, 0, 0);
      z = __builtin_amdgcn_mfma_f32_16x16x32_bf16(aq1, bk1, z, 0, 0, 0);
      s[ct] = z;
    }

    // softmax: col = ct*16+l15, rows = n0r + quad*4 + r
    float mx[4], sm[4];
#pragma unroll
    for (int r = 0; r < 4; ++r) mx[r] = -3e38f;
#pragma unroll
    for (int ct = 0; ct < 13; ++ct) {
      const bool maskct = (ct == 12) && (l15 >= 4);
#pragma unroll
      for (int r = 0; r < 4; ++r) {
        float v = s[ct][r] * 0.125f;
        if (maskct) v = -3e38f;
        s[ct][r] = v;
        mx[r] = fmaxf(mx[r], v);
      }
    }
#pragma unroll
    for (int r = 0; r < 4; ++r)
      for (int off = 1; off < 16; off <<= 1)
        mx[r] = fmaxf(mx[r], __shfl_xor(mx[r], off, 64));
#pragma unroll
    for (int r = 0; r < 4; ++r) sm[r] = 0.0f;
#pragma unroll
    for (int ct = 0; ct < 13; ++ct)
#pragma unroll
      for (int r = 0; r < 4; ++r) {
        const float p = __expf(s[ct][r] - mx[r]);
        s[ct][r] = p;
        sm[r] += p;
      }
#pragma unroll
    for (int r = 0; r < 4; ++r)
      for (int off = 1; off < 16; off <<= 1)
        sm[r] += __shfl_xor(sm[r], off, 64);

    // P -> LDS (A-layout round trip); cols 0..207 fully covered
#pragma unroll
    for (int ct = 0; ct < 13; ++ct)
#pragma unroll
      for (int r = 0; r < 4; ++r)
        Pw[(quad * 4 + r) * 208 + ct * 16 + l15] = f2bf(s[ct][r]);

    // O = P @ V: 6 full K=32 steps + masked tail (k 192..207 real)
    floatx4 oacc[4] = {};
#pragma unroll
    for (int ks = 0; ks < 6; ++ks) {
      const bf16x8 ap = *(const bf16x8*)(Pw + l15 * 208 + ks * 32 + quad * 8);
#pragma unroll
      for (int nt = 0; nt < 4; ++nt) {
        const bf16x8 bv = *(const bf16x8*)(Vt + (nt * 16 + l15) * 208 + ks * 32 + quad * 8);
        oacc[nt] = __builtin_amdgcn_mfma_f32_16x16x32_bf16(ap, bv, oacc[nt], 0, 0, 0);
      }
    }
    {
      const int off = 192 + (quad & 1) * 8;
      bf16x8 ap = *(const bf16x8*)(Pw + l15 * 208 + off);
      if (quad >= 2) ap = zerov;
#pragma unroll
      for (int nt = 0; nt < 4; ++nt) {
        const bf16x8 bv = *(const bf16x8*)(Vt + (nt * 16 + l15) * 208 + off);
        oacc[nt] = __builtin_amdgcn_mfma_f32_16x16x32_bf16(ap, bv, oacc[nt], 0, 0, 0);
      }
    }

    float rs[4];
#pragma unroll
    for (int r = 0; r < 4; ++r) rs[r] = 1.0f / sm[r];

    // O -> Pw repack -> coalesced 16B stores
#pragma unroll
    for (int nt = 0; nt < 4; ++nt)
#pragma unroll
      for (int r = 0; r < 4; ++r)
        Pw[(quad * 4 + r) * 208 + nt * 16 + l15] = f2bf(oacc[nt][r] * rs[r]);
#pragma unroll
    for (int u = lane; u < 128; u += 64) {
      const int row = u >> 3, gr = u & 7;
      const int n = n0r + row;
      if (n < 196) {
        int4 vv = *(const int4*)(Pw + row * 208 + gr * 8);
        *(int4*)(o + (size_t)gtok[n] * 768 + h * 64 + gr * 8) = vv;
      }
    }
  }
}

extern "C" void kernel_launch(void* const* d_in, const int* in_sizes, int n_in,
                              void* d_out, int out_size, void* d_ws, size_t ws_size,
                              hipStream_t stream)
{
  const void* x     = d_in[0];  // [8,3136,768]   fp32 or bf16
  const void* wqkv  = d_in[1];  // [768,2304]
  const void* wproj = d_in[2];  // [768,768]
  const void* bproj = d_in[3];  // [768]

  char* ws = (char*)d_ws;
  int*   flag   = (int*)ws;                         // 16 B
  float* bprojF = (float*)(ws + 16);                // 768 f32
  u16*   wqkvT  = (u16*)(ws + 4096);                // 2304*768 bf16
  u16*   wprojT = (u16*)(ws + 3543040);             // 768*768  bf16
  u16*   qkvbuf = (u16*)(ws + 4722688);             // 25088*2304 bf16
  u16*   xb     = (u16*)(ws + 120328192);           // 25088*768 bf16 (reused as attn out)
  u16*   attno  = xb;

  detect_k<<<1, 256, 0, stream>>>((const u16*)wqkv, flag);
  cast_x_k<<<dim3(18816), 256, 0, stream>>>(x, xb, 4816896, flag);
  ct_transpose_k<<<dim3(72, 24), 256, 0, stream>>>(wqkv, wqkvT, 768, 2304, flag);
  ct_transpose_k<<<dim3(24, 24), 256, 0, stream>>>(wproj, wprojT, 768, 768, flag);
  bias_cast_k<<<dim3(3), 256, 0, stream>>>(bproj, bprojF, 768, flag);

  // QKV: M=25088 (98 tiles), N=2304 (9 tiles), K=768 -> 882 blocks
  gemm256<<<dim3(882), 512, 0, stream>>>(xb, wqkvT, (const float*)nullptr, qkvbuf,
                                         25088, 2304, 768, flag, 0);
  attn_win<<<dim3(1536), 256, 0, stream>>>(qkvbuf, attno);
  // proj: M=25088 (98 tiles), N=768 (3 tiles), K=768 -> 294 blocks
  gemm256<<<dim3(294), 512, 0, stream>>>(attno, wprojT, bprojF, d_out,
                                         25088, 768, 768, flag, 1);
}